// Round 1
// 515.895 us; speedup vs baseline: 1.0812x; 1.0812x over previous
//
#include <hip/hip_runtime.h>

typedef __bf16 bf16;
typedef __bf16 bf16x8 __attribute__((ext_vector_type(8)));
typedef float floatx4 __attribute__((ext_vector_type(4)));

#define SCALE_QK 0.044194173824159216f
#define INV_SQRT2F 0.7071067811865476f
#define TEN  8388608L     // elems per activation tensor (4*512*4096)
#define SBAT 2097152L     // elems per batch (4096*512)
#define SPB  16777216L    // P elems per batch (4096*4096)

// address-space helper types for global_load_lds
typedef const __attribute__((address_space(1))) void GV;
typedef __attribute__((address_space(3))) void SV;

// ---------------------------------------------------------------------------
// Dtype detector (verified R3: inputs are f32 -> flag=1; bf16 -> flag=0).
// ---------------------------------------------------------------------------
__global__ __launch_bounds__(256) void detect_k(
    const unsigned* __restrict__ q, int* __restrict__ flag)
{
    __shared__ int cnt;
    if (threadIdx.x == 0) cnt = 0;
    __syncthreads();
    int c = 0;
    for (int i = threadIdx.x; i < 4096; i += 256) {
        unsigned e = (q[i] >> 7) & 0xFFu;
        c += (e >= 100u && e <= 140u) ? 1 : 0;
    }
    atomicAdd(&cnt, c);
    __syncthreads();
    if (threadIdx.x == 0) *flag = (cnt < 3000) ? 1 : 0;
}

__global__ __launch_bounds__(256) void zero_k(float* __restrict__ l)
{
    for (int i = threadIdx.x; i < 16384; i += 256) l[i] = 0.f;
}

__global__ __launch_bounds__(256) void convw_k(
    const void* w0, const void* w1, const void* w2, const void* w3,
    bf16* __restrict__ dst, const int* __restrict__ flag)
{
    const void* srcs[4] = {w0, w1, w2, w3};
    const void* s = srcs[blockIdx.y];
    bf16* d = dst + (size_t)blockIdx.y * 262144;
    const int i = (blockIdx.x * 256 + threadIdx.x) * 8;
    bf16x8 v;
    if (*flag) {
        const float* f = (const float*)s;
        #pragma unroll
        for (int r = 0; r < 8; ++r) v[r] = (bf16)f[i + r];
    } else {
        v = *(const bf16x8*)((const bf16*)s + i);
    }
    *(bf16x8*)(d + i) = v;
}

__global__ __launch_bounds__(256) void convp_k(
    const void* p0, const void* p1, const void* p2,
    const void* p3, const void* p4, const void* p5,
    float* __restrict__ dst, const int* __restrict__ flag)
{
    const void* srcs[6] = {p0, p1, p2, p3, p4, p5};
    const int f = *flag;
    for (int i = threadIdx.x; i < 3072; i += 256) {
        const void* s = srcs[i >> 9];
        const int off = i & 511;
        dst[i] = f ? ((const float*)s)[off] : (float)((const bf16*)s)[off];
    }
}

// ---------------------------------------------------------------------------
// GroupNorm: q [4][512][4096] -> XN [4][4096][512] bf16.
// ---------------------------------------------------------------------------
__global__ __launch_bounds__(256) void groupnorm_k(
    const void* __restrict__ qraw, const float* __restrict__ gamma,
    const float* __restrict__ beta, bf16* __restrict__ XN,
    const int* __restrict__ flag)
{
    const int tid = threadIdx.x;
    const int b = blockIdx.x >> 5, g = blockIdx.x & 31;
    const int f32 = *flag;
    const size_t base = ((size_t)b * 512 + (size_t)g * 16) * 4096;
    const float* sf = (const float*)qraw + base;
    const bf16*  sb = (const bf16*)qraw + base;

    float sum = 0.f, sq = 0.f;
    if (f32) {
        const floatx4* v4 = (const floatx4*)sf;
        for (int idx = tid; idx < 16384; idx += 256) {
            floatx4 v = v4[idx];
            #pragma unroll
            for (int r = 0; r < 4; ++r) { float f = v[r]; sum += f; sq += f * f; }
        }
    } else {
        const bf16x8* v8 = (const bf16x8*)sb;
        for (int idx = tid; idx < 8192; idx += 256) {
            bf16x8 v = v8[idx];
            #pragma unroll
            for (int r = 0; r < 8; ++r) { float f = (float)v[r]; sum += f; sq += f * f; }
        }
    }
    #pragma unroll
    for (int off = 32; off; off >>= 1) {
        sum += __shfl_down(sum, off);
        sq  += __shfl_down(sq, off);
    }
    __shared__ float sS[4], sQ[4];
    __shared__ float s_mean, s_rstd;
    const int wave = tid >> 6, lane = tid & 63;
    if (lane == 0) { sS[wave] = sum; sQ[wave] = sq; }
    __syncthreads();
    if (tid == 0) {
        float ts = sS[0] + sS[1] + sS[2] + sS[3];
        float tq = sQ[0] + sQ[1] + sQ[2] + sQ[3];
        float mean = ts * (1.0f / 65536.0f);
        float var  = tq * (1.0f / 65536.0f) - mean * mean;
        s_mean = mean;
        s_rstd = rsqrtf(fmaxf(var, 0.f) + 1e-6f);
    }
    __syncthreads();
    const float mean = s_mean, rstd = s_rstd;

    float ga[16], be[16];
    #pragma unroll
    for (int c = 0; c < 16; ++c) {
        ga[c] = gamma[g * 16 + c] * rstd;
        be[c] = beta[g * 16 + c] - mean * ga[c];
    }
    bf16* dst = XN + (size_t)b * SBAT + (size_t)g * 16;
    for (int p0 = 0; p0 < 4096; p0 += 256) {
        const int p = p0 + tid;
        bf16x8 o0, o1;
        #pragma unroll
        for (int c = 0; c < 8; ++c) {
            float v = f32 ? sf[(size_t)c * 4096 + p] : (float)sb[(size_t)c * 4096 + p];
            o0[c] = (bf16)(v * ga[c] + be[c]);
        }
        #pragma unroll
        for (int c = 0; c < 8; ++c) {
            float v = f32 ? sf[(size_t)(c + 8) * 4096 + p] : (float)sb[(size_t)(c + 8) * 4096 + p];
            o1[c] = (bf16)(v * ga[c + 8] + be[c + 8]);
        }
        bf16* dp = dst + (size_t)p * 512;
        *(bf16x8*)dp = o0;
        *(bf16x8*)(dp + 8) = o1;
    }
}

// ---------------------------------------------------------------------------
// Reduce split-K partials: AOt = (P0 + P1) / l.  Part: [2][4][4096][512] bf16.
// ---------------------------------------------------------------------------
__global__ __launch_bounds__(256) void reduce_k(
    const bf16* __restrict__ Part, const float* __restrict__ lbuf,
    bf16* __restrict__ AOt)
{
    const size_t i8 = ((size_t)blockIdx.x * 256 + threadIdx.x) * 8;
    const int b = (int)(i8 >> 21);
    const int j = (int)((i8 >> 9) & 4095);
    const float rl = 1.0f / fmaxf(lbuf[b * 4096 + j], 1e-30f);
    bf16x8 a = *(const bf16x8*)&Part[i8];
    bf16x8 c = *(const bf16x8*)&Part[TEN + i8];
    bf16x8 o;
    #pragma unroll
    for (int r = 0; r < 8; ++r) o[r] = (bf16)(((float)a[r] + (float)c[r]) * rl);
    *(bf16x8*)&AOt[i8] = o;
}

// ---------------------------------------------------------------------------
// C = X · Y^T GEMM, k-contiguous operands, 128x128x32 tiles, 4 waves (2x2),
// 16x16x32 bf16 MFMA. Double-buffered LDS with direct global->LDS staging
// (global_load_lds width 16): loads for iter k+1 in flight during MFMA(k),
// single barrier per K-iter (the barrier's vmcnt(0) drain is the handoff).
// XCD-aware 2D block swizzle keeps each XCD's operand working set L2-resident.
// Epilogues (all bf16 outs staged through LDS for coalesced 16B stores):
//   0: C = acc + bias[n]                          (Q/K proj, C=[p][o])
//   1: C = acc + bias[m]                          (V proj,   C=[o][p])
//   2: C = exp(min(acc*SCALE,30)); atomic rowsum  (scores -> P)
//   3: C = acc / l[m]                             (PV, fallback path)
//   4: C = (acc + bias[m] + res) * INV_SQRT2      (out proj + residual)
//   5: C = acc  (PV split-K partial; z = batch*2 + split, hardcoded map)
// ---------------------------------------------------------------------------
template <int EPI>
__global__ __launch_bounds__(256, 4) void gemm_xyt(
    const bf16* __restrict__ Xb, const bf16* __restrict__ Yb,
    void* __restrict__ Cv, int N, int K, int lda, int ldb,
    long sX, long sY, long sC,
    const float* __restrict__ bias,
    float* __restrict__ lbuf, long sL,
    const void* __restrict__ res, long sR,
    const int* __restrict__ flag)
{
    __shared__ __align__(16) bf16 smem[17408];   // 32KB dbuf, 34KB epilogue

    const int tid  = threadIdx.x;
    const int wave = tid >> 6;
    const int lane = tid & 63;
    const int z = blockIdx.z;

    // ---- XCD-aware block swizzle: each XCD gets a contiguous 2D region ----
    // (global dispatch id = z*gx*gy + by*gx + bx round-robins XCDs; gx*gy is
    //  divisible by 8 for every launch shape here, so o%8 == XCD id.)
    int bx = blockIdx.x, by = blockIdx.y;
    {
        const int gx = gridDim.x, gy = gridDim.y;
        const int o = by * gx + bx;
        const int xcd = o & 7, idx = o >> 3;
        if (gx == 32 && gy == 32) {          // scores: 16x8 regions (2MB+1MB < L2)
            bx = (xcd & 1) * 16 + (idx & 15);
            by = (xcd >> 1) * 8 + (idx >> 4);
        } else if (gx == 4) {                // Q/K proj + PV: 4x4 regions
            bx = idx & 3;
            by = xcd * 4 + (idx >> 2);
        } else if (gx == 32 && gy == 4) {    // V/out proj: 16x1 regions
            bx = (xcd & 1) * 16 + (idx & 15);
            by = xcd >> 1;
        }
    }

    const bf16* X; const bf16* Y; bf16* Cb; float* Cf = nullptr;
    int zb = z;
    if (EPI == 5) {
        const int b = z >> 1, s = z & 1;
        X  = Xb + (size_t)b * SPB  + (size_t)s * 2048;
        Y  = Yb + (size_t)b * SBAT + (size_t)s * 2048;
        Cb = (bf16*)Cv + (size_t)s * TEN + (size_t)b * SBAT;
        zb = b;
    } else {
        X  = Xb + (long)z * sX;
        Y  = Yb + (long)z * sY;
        Cb = (bf16*)Cv  + (long)z * sC;
        Cf = (float*)Cv + (long)z * sC;
    }
    const int f32o = (EPI == 4) ? *flag : 0;

    const int m0 = by * 128, n0 = bx * 128;
    const int wm = (wave >> 1) * 64, wn = (wave & 1) * 64;
    const int fr = lane & 15, quad = lane >> 4;

    // staging: thread covers rows {srow, srow+64} x 8 cols of A and B tiles.
    // LDS dest is exactly base + tid*16 bytes per 4KB region (lane-linear,
    // as global_load_lds requires).
    const int srow = tid >> 2;
    const int scol = (tid & 3) * 8;
    const bf16* pX = X + (size_t)(m0 + srow) * lda + scol;
    const bf16* pY = Y + (size_t)(n0 + srow) * ldb + scol;
    const size_t oX = (size_t)64 * lda, oY = (size_t)64 * ldb;
    char* const sb0 = (char*)smem;
    const int ldst = tid * 16;

    auto stage = [&](int k, int pb) {
        char* d = sb0 + pb * 16384;
        const bf16* x = pX + k * 32;
        const bf16* y = pY + k * 32;
        __builtin_amdgcn_global_load_lds((GV*)x,        (SV*)(d + ldst),         16, 0, 0);
        __builtin_amdgcn_global_load_lds((GV*)(x + oX), (SV*)(d + 4096 + ldst),  16, 0, 0);
        __builtin_amdgcn_global_load_lds((GV*)y,        (SV*)(d + 8192 + ldst),  16, 0, 0);
        __builtin_amdgcn_global_load_lds((GV*)(y + oY), (SV*)(d + 12288 + ldst), 16, 0, 0);
    };

    floatx4 acc[4][4] = {};
    const int NK = K >> 5;

    stage(0, 0);
    __syncthreads();                        // vmcnt(0) drain: buf0 ready

    for (int k = 0; k < NK; ++k) {
        const int p = k & 1;
        if (k + 1 < NK) stage(k + 1, 1 - p);   // async into other buffer
        const bf16* bA = smem + p * 8192;
        const bf16* bB = bA + 4096;
        bf16x8 af[4], bfr[4];
        #pragma unroll
        for (int i = 0; i < 4; ++i) {
            af[i]  = *(const bf16x8*)&bA[(wm + i * 16 + fr) * 32 + quad * 8];
            bfr[i] = *(const bf16x8*)&bB[(wn + i * 16 + fr) * 32 + quad * 8];
        }
        #pragma unroll
        for (int i = 0; i < 4; ++i)
            #pragma unroll
            for (int j = 0; j < 4; ++j)
                acc[i][j] = __builtin_amdgcn_mfma_f32_16x16x32_bf16(
                    af[i], bfr[j], acc[i][j], 0, 0, 0);
        __syncthreads();                    // drains stage(k+1), protects bufs
    }

    // ---- finalize values in-place (lane holds D[quad*4+r][fr] per frag) ----
    #pragma unroll
    for (int i = 0; i < 4; ++i) {
        const int mg = m0 + wm + i * 16 + quad * 4;
        float bmr[4], rl[4];
        if (EPI == 1 || EPI == 4) {
            #pragma unroll
            for (int r = 0; r < 4; ++r) bmr[r] = bias[mg + r];
        }
        if (EPI == 3) {
            #pragma unroll
            for (int r = 0; r < 4; ++r)
                rl[r] = 1.0f / fmaxf(lbuf[zb * sL + mg + r], 1e-30f);
        }
        if (EPI == 2) {
            float rs[4] = {0.f, 0.f, 0.f, 0.f};
            #pragma unroll
            for (int j = 0; j < 4; ++j)
                #pragma unroll
                for (int r = 0; r < 4; ++r) {
                    float e = __expf(fminf(acc[i][j][r] * SCALE_QK, 30.f));
                    acc[i][j][r] = e;
                    rs[r] += e;
                }
            #pragma unroll
            for (int r = 0; r < 4; ++r) {
                float v = rs[r];
                v += __shfl_xor(v, 1);
                v += __shfl_xor(v, 2);
                v += __shfl_xor(v, 4);
                v += __shfl_xor(v, 8);
                if (fr == 0) atomicAdd(&lbuf[zb * sL + mg + r], v);
            }
        } else if (EPI != 5) {
            #pragma unroll
            for (int j = 0; j < 4; ++j) {
                const int ng = n0 + wn + j * 16 + fr;
                #pragma unroll
                for (int r = 0; r < 4; ++r) {
                    float v = acc[i][j][r];
                    if (EPI == 0) v += bias[ng];
                    if (EPI == 1) v += bmr[r];
                    if (EPI == 3) v *= rl[r];
                    if (EPI == 4) v += bmr[r];   // residual+scale at readout
                    acc[i][j][r] = v;
                }
            }
        }
    }

    // ---- staged, coalesced stores ----
    if (EPI != 4) {
        bf16* ct = smem;                       // [128][132] bf16
        #pragma unroll
        for (int i = 0; i < 4; ++i)
            #pragma unroll
            for (int j = 0; j < 4; ++j)
                #pragma unroll
                for (int r = 0; r < 4; ++r)
                    ct[(wm + i * 16 + quad * 4 + r) * 132 + wn + j * 16 + fr] =
                        (bf16)acc[i][j][r];
        __syncthreads();
        #pragma unroll
        for (int w = 0; w < 8; ++w) {
            const int idx = w * 2048 + tid * 8;
            const int row = idx >> 7, col = idx & 127;
            bf16x8 v = *(const bf16x8*)&ct[row * 132 + col];
            *(bf16x8*)&Cb[(size_t)(m0 + row) * N + n0 + col] = v;
        }
    } else if (f32o) {
        float* ct = (float*)smem;              // [64][132] f32, two halves
        const float* rres = (const float*)res + (size_t)z * sR;
        #pragma unroll
        for (int h = 0; h < 2; ++h) {
            if ((wave >> 1) == h) {
                #pragma unroll
                for (int i = 0; i < 4; ++i)
                    #pragma unroll
                    for (int j = 0; j < 4; ++j)
                        #pragma unroll
                        for (int r = 0; r < 4; ++r)
                            ct[(i * 16 + quad * 4 + r) * 132 + wn + j * 16 + fr] =
                                acc[i][j][r];
            }
            __syncthreads();
            #pragma unroll
            for (int w = 0; w < 8; ++w) {
                const int idx = (w * 256 + tid) * 4;
                const int row = idx >> 7, col = idx & 127;
                const size_t o = (size_t)(m0 + h * 64 + row) * N + n0 + col;
                floatx4 v = *(const floatx4*)&ct[row * 132 + col];
                floatx4 rv = *(const floatx4*)&rres[o];
                #pragma unroll
                for (int e = 0; e < 4; ++e) v[e] = (v[e] + rv[e]) * INV_SQRT2F;
                *(floatx4*)&Cf[o] = v;
            }
            __syncthreads();
        }
    } else {
        // bf16-residual fallback (correctness path; not hit with f32 inputs)
        const bf16* resb = (const bf16*)res + (size_t)z * sR;
        #pragma unroll
        for (int i = 0; i < 4; ++i) {
            const int mg = m0 + wm + i * 16 + quad * 4;
            #pragma unroll
            for (int j = 0; j < 4; ++j) {
                const int ng = n0 + wn + j * 16 + fr;
                #pragma unroll
                for (int r = 0; r < 4; ++r) {
                    const size_t o = (size_t)(mg + r) * N + ng;
                    Cb[o] = (bf16)((acc[i][j][r] + (float)resb[o]) * INV_SQRT2F);
                }
            }
        }
    }
}

// ---------------------------------------------------------------------------
extern "C" void kernel_launch(void* const* d_in, const int* in_sizes, int n_in,
                              void* d_out, int out_size, void* d_ws, size_t ws_size,
                              hipStream_t stream)
{
    const void* q     = d_in[0];
    const void* gamma = d_in[1];
    const void* beta  = d_in[2];
    const void* wq    = d_in[3];
    const void* bq    = d_in[4];
    const void* wk    = d_in[5];
    const void* bk    = d_in[6];
    const void* wv    = d_in[7];
    const void* bv    = d_in[8];
    const void* wo    = d_in[9];
    const void* bo    = d_in[10];

    char* w = (char*)d_ws;
    int*   flag = (int*)w;   w += 16;
    float* Pf   = (float*)w; w += 6 * 512 * 4;      // gamma,beta,bq,bk,bv,bo
    bf16*  Wc   = (bf16*)w;  w += 4 * 262144 * 2;   // wq,wk,wv,wo bf16
    bf16*  XN   = (bf16*)w;  w += TEN * 2;          // reused as AOt
    bf16*  Qt   = (bf16*)w;  w += TEN * 2;
    bf16*  V    = (bf16*)w;  w += TEN * 2;
    float* lbuf = (float*)w; w += (size_t)4 * 4096 * 4;
    bf16*  P    = (bf16*)w;
    const size_t base_need = (size_t)(w - (char*)d_ws);
    const bool full = ws_size >= base_need + (size_t)4 * 4096 * 4096 * 2;

    bf16* Kt   = (bf16*)d_out;   // scratch: dead before PV partials land
    bf16* Part = (bf16*)d_out;   // split-K partials [2][4][4096][512]
    bf16* AOt  = XN;

    detect_k<<<dim3(1), 256, 0, stream>>>((const unsigned*)q, flag);
    zero_k<<<dim3(1), 256, 0, stream>>>(lbuf);
    convw_k<<<dim3(128, 4), 256, 0, stream>>>(wq, wk, wv, wo, Wc, flag);
    convp_k<<<dim3(1), 256, 0, stream>>>(gamma, beta, bq, bk, bv, bo, Pf, flag);

    groupnorm_k<<<dim3(128), 256, 0, stream>>>(q, Pf, Pf + 512, XN, flag);

    // Qt[p][o] = XN . Wq^T + bq ; Kt likewise.  N=512, K=512
    gemm_xyt<0><<<dim3(4, 32, 4), 256, 0, stream>>>(XN, Wc + 0 * 262144, Qt,
        512, 512, 512, 512, SBAT, 0, SBAT, Pf + 1024, nullptr, 0, nullptr, 0, flag);
    gemm_xyt<0><<<dim3(4, 32, 4), 256, 0, stream>>>(XN, Wc + 1 * 262144, Kt,
        512, 512, 512, 512, SBAT, 0, SBAT, Pf + 1536, nullptr, 0, nullptr, 0, flag);
    // V[o][p] = Wv . XN^T + bv.  N=4096, K=512
    gemm_xyt<1><<<dim3(32, 4, 4), 256, 0, stream>>>(Wc + 2 * 262144, XN, V,
        4096, 512, 512, 512, 0, SBAT, SBAT, Pf + 2048, nullptr, 0, nullptr, 0, flag);

    if (full) {
        // P[j][i] = exp(scale*<Qt[j],Kt[i]>); lbuf[b][j] += rowsums
        gemm_xyt<2><<<dim3(32, 32, 4), 256, 0, stream>>>(Qt, Kt, P,
            4096, 512, 512, 512, SBAT, SBAT, SPB, nullptr, lbuf, 4096,
            nullptr, 0, flag);
        // PV split-K x2 partials (z = b*2 + s), K=2048 each
        gemm_xyt<5><<<dim3(4, 32, 8), 256, 0, stream>>>(P, V, Part,
            512, 2048, 4096, 4096, 0, 0, 0, nullptr, nullptr, 0,
            nullptr, 0, flag);
        // AOt = (P0 + P1) / l
        reduce_k<<<dim3(4096), 256, 0, stream>>>(Part, lbuf, AOt);
    } else {
        for (int b = 0; b < 4; ++b) {
            gemm_xyt<2><<<dim3(32, 32, 1), 256, 0, stream>>>(
                Qt + (size_t)b * SBAT, Kt + (size_t)b * SBAT, P,
                4096, 512, 512, 512, 0, 0, 0, nullptr,
                lbuf + (size_t)b * 4096, 0, nullptr, 0, flag);
            gemm_xyt<3><<<dim3(4, 32, 1), 256, 0, stream>>>(
                P, V + (size_t)b * SBAT, AOt + (size_t)b * SBAT,
                512, 4096, 4096, 4096, 0, 0, 0, nullptr,
                lbuf + (size_t)b * 4096, 0, nullptr, 0, flag);
        }
    }

    // out[o][p] = (Wo . AOt^T + bo + q) * inv_sqrt2.  N=4096, K=512
    gemm_xyt<4><<<dim3(32, 4, 4), 256, 0, stream>>>(Wc + 3 * 262144, AOt, d_out,
        4096, 512, 512, 512, 0, SBAT, SBAT, Pf + 2560, nullptr, 0, q, SBAT, flag);
}

// Round 2
// 484.706 us; speedup vs baseline: 1.1507x; 1.0643x over previous
//
#include <hip/hip_runtime.h>

typedef __bf16 bf16;
typedef __bf16 bf16x8 __attribute__((ext_vector_type(8)));
typedef float floatx4 __attribute__((ext_vector_type(4)));

#define SCALE_QK 0.044194173824159216f
#define INV_SQRT2F 0.7071067811865476f
#define TEN  8388608L     // elems per activation tensor (4*512*4096)
#define SBAT 2097152L     // elems per batch (4096*512)
#define SPB  16777216L    // P elems per batch (4096*4096)

// address-space helper types for global_load_lds
typedef const __attribute__((address_space(1))) void GV;
typedef __attribute__((address_space(3))) void SV;

// ---------------------------------------------------------------------------
// Dtype detector (verified R3: inputs are f32 -> flag=1; bf16 -> flag=0).
// ---------------------------------------------------------------------------
__global__ __launch_bounds__(256) void detect_k(
    const unsigned* __restrict__ q, int* __restrict__ flag)
{
    __shared__ int cnt;
    if (threadIdx.x == 0) cnt = 0;
    __syncthreads();
    int c = 0;
    for (int i = threadIdx.x; i < 4096; i += 256) {
        unsigned e = (q[i] >> 7) & 0xFFu;
        c += (e >= 100u && e <= 140u) ? 1 : 0;
    }
    atomicAdd(&cnt, c);
    __syncthreads();
    if (threadIdx.x == 0) *flag = (cnt < 3000) ? 1 : 0;
}

__global__ __launch_bounds__(256) void zero_k(float* __restrict__ l)
{
    for (int i = threadIdx.x; i < 16384; i += 256) l[i] = 0.f;
}

__global__ __launch_bounds__(256) void convw_k(
    const void* w0, const void* w1, const void* w2, const void* w3,
    bf16* __restrict__ dst, const int* __restrict__ flag)
{
    const void* srcs[4] = {w0, w1, w2, w3};
    const void* s = srcs[blockIdx.y];
    bf16* d = dst + (size_t)blockIdx.y * 262144;
    const int i = (blockIdx.x * 256 + threadIdx.x) * 8;
    bf16x8 v;
    if (*flag) {
        const float* f = (const float*)s;
        #pragma unroll
        for (int r = 0; r < 8; ++r) v[r] = (bf16)f[i + r];
    } else {
        v = *(const bf16x8*)((const bf16*)s + i);
    }
    *(bf16x8*)(d + i) = v;
}

__global__ __launch_bounds__(256) void convp_k(
    const void* p0, const void* p1, const void* p2,
    const void* p3, const void* p4, const void* p5,
    float* __restrict__ dst, const int* __restrict__ flag)
{
    const void* srcs[6] = {p0, p1, p2, p3, p4, p5};
    const int f = *flag;
    for (int i = threadIdx.x; i < 3072; i += 256) {
        const void* s = srcs[i >> 9];
        const int off = i & 511;
        dst[i] = f ? ((const float*)s)[off] : (float)((const bf16*)s)[off];
    }
}

// ---------------------------------------------------------------------------
// GroupNorm: q [4][512][4096] -> XN [4][4096][512] bf16.
// ---------------------------------------------------------------------------
__global__ __launch_bounds__(256) void groupnorm_k(
    const void* __restrict__ qraw, const float* __restrict__ gamma,
    const float* __restrict__ beta, bf16* __restrict__ XN,
    const int* __restrict__ flag)
{
    const int tid = threadIdx.x;
    const int b = blockIdx.x >> 5, g = blockIdx.x & 31;
    const int f32 = *flag;
    const size_t base = ((size_t)b * 512 + (size_t)g * 16) * 4096;
    const float* sf = (const float*)qraw + base;
    const bf16*  sb = (const bf16*)qraw + base;

    float sum = 0.f, sq = 0.f;
    if (f32) {
        const floatx4* v4 = (const floatx4*)sf;
        for (int idx = tid; idx < 16384; idx += 256) {
            floatx4 v = v4[idx];
            #pragma unroll
            for (int r = 0; r < 4; ++r) { float f = v[r]; sum += f; sq += f * f; }
        }
    } else {
        const bf16x8* v8 = (const bf16x8*)sb;
        for (int idx = tid; idx < 8192; idx += 256) {
            bf16x8 v = v8[idx];
            #pragma unroll
            for (int r = 0; r < 8; ++r) { float f = (float)v[r]; sum += f; sq += f * f; }
        }
    }
    #pragma unroll
    for (int off = 32; off; off >>= 1) {
        sum += __shfl_down(sum, off);
        sq  += __shfl_down(sq, off);
    }
    __shared__ float sS[4], sQ[4];
    __shared__ float s_mean, s_rstd;
    const int wave = tid >> 6, lane = tid & 63;
    if (lane == 0) { sS[wave] = sum; sQ[wave] = sq; }
    __syncthreads();
    if (tid == 0) {
        float ts = sS[0] + sS[1] + sS[2] + sS[3];
        float tq = sQ[0] + sQ[1] + sQ[2] + sQ[3];
        float mean = ts * (1.0f / 65536.0f);
        float var  = tq * (1.0f / 65536.0f) - mean * mean;
        s_mean = mean;
        s_rstd = rsqrtf(fmaxf(var, 0.f) + 1e-6f);
    }
    __syncthreads();
    const float mean = s_mean, rstd = s_rstd;

    float ga[16], be[16];
    #pragma unroll
    for (int c = 0; c < 16; ++c) {
        ga[c] = gamma[g * 16 + c] * rstd;
        be[c] = beta[g * 16 + c] - mean * ga[c];
    }
    bf16* dst = XN + (size_t)b * SBAT + (size_t)g * 16;
    for (int p0 = 0; p0 < 4096; p0 += 256) {
        const int p = p0 + tid;
        bf16x8 o0, o1;
        #pragma unroll
        for (int c = 0; c < 8; ++c) {
            float v = f32 ? sf[(size_t)c * 4096 + p] : (float)sb[(size_t)c * 4096 + p];
            o0[c] = (bf16)(v * ga[c] + be[c]);
        }
        #pragma unroll
        for (int c = 0; c < 8; ++c) {
            float v = f32 ? sf[(size_t)(c + 8) * 4096 + p] : (float)sb[(size_t)(c + 8) * 4096 + p];
            o1[c] = (bf16)(v * ga[c + 8] + be[c + 8]);
        }
        bf16* dp = dst + (size_t)p * 512;
        *(bf16x8*)dp = o0;
        *(bf16x8*)(dp + 8) = o1;
    }
}

// ---------------------------------------------------------------------------
// Reduce split-K partials: AOt = (P0 + P1) / l.  Part: [2][4][4096][512] bf16.
// ---------------------------------------------------------------------------
__global__ __launch_bounds__(256) void reduce_k(
    const bf16* __restrict__ Part, const float* __restrict__ lbuf,
    bf16* __restrict__ AOt)
{
    const size_t i8 = ((size_t)blockIdx.x * 256 + threadIdx.x) * 8;
    const int b = (int)(i8 >> 21);
    const int j = (int)((i8 >> 9) & 4095);
    const float rl = 1.0f / fmaxf(lbuf[b * 4096 + j], 1e-30f);
    bf16x8 a = *(const bf16x8*)&Part[i8];
    bf16x8 c = *(const bf16x8*)&Part[TEN + i8];
    bf16x8 o;
    #pragma unroll
    for (int r = 0; r < 8; ++r) o[r] = (bf16)(((float)a[r] + (float)c[r]) * rl);
    *(bf16x8*)&AOt[i8] = o;
}

// ---------------------------------------------------------------------------
// 256x256 8-phase counted-vmcnt GEMM (T2+T3+T4+T5), C = X . Y^T, k-contig.
// 8 waves (2M x 4N), half-K-tile slot = 32 k-cols of A(256) + B(256) = 32KB,
// 4 slots = 128KB LDS, prefetch depth 3 half-tiles, vmcnt(8) steady state
// (4 loads/stage x 2 newest stages in flight), raw s_barrier (no drain).
// LDS XOR-swizzle byte ^= ((row>>1)&3)<<4 : both-sides (pre-swizzled global
// source + swizzled ds_read; global_load_lds dest stays lane-linear).
// Per half-tile: 2 phases x {ds_read ; stage ; barrier ; 16 MFMA ; barrier}.
// Epilogues: 2 = exp(min(acc*SCALE,30)) + atomic rowsum -> P
//            5 = plain store (PV split-K partial, z = b*2 + s)
// ---------------------------------------------------------------------------
template <int EPI>
__global__ __launch_bounds__(512, 2) void gemm8(
    const bf16* __restrict__ Xb, const bf16* __restrict__ Yb,
    bf16* __restrict__ Cv, int N, int K, int lda, int ldb,
    long sX, long sY, long sC, float* __restrict__ lbuf, long sL)
{
    __shared__ __align__(16) char smc[131072];

    const int tid  = threadIdx.x;
    const int wave = tid >> 6;
    const int lane = tid & 63;
    const int z = blockIdx.z;

    // XCD-aware swizzle: contiguous 2D region per XCD (bijective; gx*gy%8==0)
    int bx = blockIdx.x, by = blockIdx.y;
    {
        const int o = by * gridDim.x + bx;
        const int xcd = o & 7, idx = o >> 3;
        if (gridDim.x == 16) {               // scores 16x16: 4m x 8n regions
            by = (xcd >> 1) * 4 + (idx & 3);
            bx = (xcd & 1) * 8 + (idx >> 2);
        } else {                             // PV 2x16: 2m x 2n regions
            bx = idx & 1;
            by = xcd * 2 + (idx >> 1);
        }
    }

    const bf16* X; const bf16* Y; bf16* Cb;
    if (EPI == 5) {
        const int b = z >> 1, s = z & 1;
        X  = Xb + (size_t)b * SPB  + (size_t)s * 2048;
        Y  = Yb + (size_t)b * SBAT + (size_t)s * 2048;
        Cb = Cv + (size_t)s * TEN + (size_t)b * SBAT;
    } else {
        X  = Xb + (long)z * sX;
        Y  = Yb + (long)z * sY;
        Cb = Cv + (long)z * sC;
    }

    const int m0 = by * 256, n0 = bx * 256;
    const int wm = (wave >> 2) * 128, wn = (wave & 3) * 64;
    const int fr = lane & 15, quad = lane >> 4;

    // ---- staging: thread t -> rows {t>>2, 128+(t>>2)} of A and B, 16B each.
    // LDS dest lane-linear (t*16); source col pre-swizzled so that LDS slot
    // (row, s) holds logical col s^((row>>1)&3)  (rows r and r+128 share the
    // mask bits, so one c8 serves all four loads).
    const int tq = tid >> 2;
    const int c8 = ((tid & 3) ^ ((tid >> 3) & 3)) << 3;
    const bf16* gA0 = X + (size_t)(m0 + tq) * lda + c8;
    const bf16* gA1 = gA0 + (size_t)128 * lda;
    const bf16* gB0 = Y + (size_t)(n0 + tq) * ldb + c8;
    const bf16* gB1 = gB0 + (size_t)128 * ldb;
    const int ldst = tid * 16;

    auto stage = [&](int h) {
        char* d = smc + ((h & 3) << 15);
        const int ko = h << 5;
        __builtin_amdgcn_global_load_lds((GV*)(gA0 + ko), (SV*)(d + ldst),         16, 0, 0);
        __builtin_amdgcn_global_load_lds((GV*)(gA1 + ko), (SV*)(d + 8192  + ldst), 16, 0, 0);
        __builtin_amdgcn_global_load_lds((GV*)(gB0 + ko), (SV*)(d + 16384 + ldst), 16, 0, 0);
        __builtin_amdgcn_global_load_lds((GV*)(gB1 + ko), (SV*)(d + 24576 + ldst), 16, 0, 0);
    };

    // ---- fragment read addresses (swizzled; row bits [3:1] come from fr) --
    const int swz = (quad ^ ((fr >> 1) & 3)) << 4;
    const int lbA = (wm + fr) * 64 + swz;            // + m*1024
    const int lbB = 16384 + (wn + fr) * 64 + swz;    // + n*1024

    floatx4 acc[8][4] = {};
    const int H = K >> 5;        // half-tiles (32 k-cols each); H >= 4 always

    stage(0); stage(1); stage(2);
    asm volatile("s_waitcnt vmcnt(8)" ::: "memory");   // slot0 landed (mine)
    __builtin_amdgcn_s_barrier();                      // ... and everyone's

    #pragma unroll 1
    for (int h = 0; h < H; ++h) {
        const char* sb = smc + ((h & 3) << 15);
        bf16x8 Bf[4], Af[4];
        // ---- phase A: B-frags + A-frags(m 0..3) ; prefetch h+3 ----
        #pragma unroll
        for (int n = 0; n < 4; ++n) Bf[n] = *(const bf16x8*)(sb + lbB + n * 1024);
        #pragma unroll
        for (int m = 0; m < 4; ++m) Af[m] = *(const bf16x8*)(sb + lbA + m * 1024);
        if (h + 3 < H) stage(h + 3);   // overwrites slot (h-1): drained below
        __builtin_amdgcn_s_barrier();
        __builtin_amdgcn_s_setprio(1);
        #pragma unroll
        for (int m = 0; m < 4; ++m)
            #pragma unroll
            for (int n = 0; n < 4; ++n)
                acc[m][n] = __builtin_amdgcn_mfma_f32_16x16x32_bf16(
                    Af[m], Bf[n], acc[m][n], 0, 0, 0);
        __builtin_amdgcn_s_setprio(0);
        __builtin_amdgcn_s_barrier();
        // ---- phase B: A-frags(m 4..7) ----
        #pragma unroll
        for (int m = 0; m < 4; ++m) Af[m] = *(const bf16x8*)(sb + lbA + (4 + m) * 1024);
        __builtin_amdgcn_s_barrier();
        __builtin_amdgcn_s_setprio(1);
        #pragma unroll
        for (int m = 0; m < 4; ++m)
            #pragma unroll
            for (int n = 0; n < 4; ++n)
                acc[4 + m][n] = __builtin_amdgcn_mfma_f32_16x16x32_bf16(
                    Af[m], Bf[n], acc[4 + m][n], 0, 0, 0);
        __builtin_amdgcn_s_setprio(0);
        // slot(h+1) readiness: keep the 2 newest stages (h+2,h+3) in flight
        if (h + 3 < H)      { asm volatile("s_waitcnt vmcnt(8)" ::: "memory"); }
        else if (h + 2 < H) { asm volatile("s_waitcnt vmcnt(4)" ::: "memory"); }
        else if (h + 1 < H) { asm volatile("s_waitcnt vmcnt(0)" ::: "memory"); }
        __builtin_amdgcn_s_barrier();   // collectivize readiness + fence reuse
    }
    asm volatile("s_waitcnt vmcnt(0)" ::: "memory");
    __syncthreads();

    // ---- finalize (lane holds D[quad*4+r][fr] of frag (m,n)) ----
    if (EPI == 2) {
        #pragma unroll
        for (int m = 0; m < 8; ++m) {
            const int mg = m0 + wm + m * 16 + quad * 4;
            float rs[4] = {0.f, 0.f, 0.f, 0.f};
            #pragma unroll
            for (int n = 0; n < 4; ++n)
                #pragma unroll
                for (int r = 0; r < 4; ++r) {
                    float e = __expf(fminf(acc[m][n][r] * SCALE_QK, 30.f));
                    acc[m][n][r] = e;
                    rs[r] += e;
                }
            #pragma unroll
            for (int r = 0; r < 4; ++r) {
                float v = rs[r];
                v += __shfl_xor(v, 1);
                v += __shfl_xor(v, 2);
                v += __shfl_xor(v, 4);
                v += __shfl_xor(v, 8);
                if (fr == 0) atomicAdd(&lbuf[z * sL + mg + r], v);
            }
        }
    }

    // ---- staged coalesced stores, two 128-row halves through LDS ----
    bf16* ct = (bf16*)smc;                 // [128][260] bf16 = 66.5KB
    const int myhalf = wave >> 2;          // waves 0-3: rows 0-127
    #pragma unroll
    for (int half = 0; half < 2; ++half) {
        if (myhalf == half) {
            #pragma unroll
            for (int m = 0; m < 8; ++m)
                #pragma unroll
                for (int n = 0; n < 4; ++n)
                    #pragma unroll
                    for (int r = 0; r < 4; ++r)
                        ct[(m * 16 + quad * 4 + r) * 260 + wn + n * 16 + fr] =
                            (bf16)acc[m][n][r];
        }
        __syncthreads();
        #pragma unroll
        for (int w = 0; w < 8; ++w) {
            const int idx = (w * 512 + tid) * 8;
            const int row = idx >> 8, col = idx & 255;
            bf16x8 v = *(const bf16x8*)&ct[row * 260 + col];
            *(bf16x8*)&Cb[(size_t)(m0 + half * 128 + row) * N + n0 + col] = v;
        }
        __syncthreads();
    }
}

// ---------------------------------------------------------------------------
// 128x128x32 2-phase GEMM (kept for projections + fallback path).
// Epilogues: 0 bias[n] ; 1 bias[m] ; 2 exp+rowsum ; 3 acc/l ; 4 out+res ; 5 raw
// ---------------------------------------------------------------------------
template <int EPI>
__global__ __launch_bounds__(256, 4) void gemm_xyt(
    const bf16* __restrict__ Xb, const bf16* __restrict__ Yb,
    void* __restrict__ Cv, int N, int K, int lda, int ldb,
    long sX, long sY, long sC,
    const float* __restrict__ bias,
    float* __restrict__ lbuf, long sL,
    const void* __restrict__ res, long sR,
    const int* __restrict__ flag)
{
    __shared__ __align__(16) bf16 smem[17408];   // 32KB dbuf, 34KB epilogue

    const int tid  = threadIdx.x;
    const int wave = tid >> 6;
    const int lane = tid & 63;
    const int z = blockIdx.z;

    int bx = blockIdx.x, by = blockIdx.y;
    {
        const int gx = gridDim.x, gy = gridDim.y;
        const int o = by * gx + bx;
        const int xcd = o & 7, idx = o >> 3;
        if (gx == 32 && gy == 32) {
            bx = (xcd & 1) * 16 + (idx & 15);
            by = (xcd >> 1) * 8 + (idx >> 4);
        } else if (gx == 4) {
            bx = idx & 3;
            by = xcd * 4 + (idx >> 2);
        } else if (gx == 32 && gy == 4) {
            bx = (xcd & 1) * 16 + (idx & 15);
            by = xcd >> 1;
        }
    }

    const bf16* X; const bf16* Y; bf16* Cb; float* Cf = nullptr;
    int zb = z;
    if (EPI == 5) {
        const int b = z >> 1, s = z & 1;
        X  = Xb + (size_t)b * SPB  + (size_t)s * 2048;
        Y  = Yb + (size_t)b * SBAT + (size_t)s * 2048;
        Cb = (bf16*)Cv + (size_t)s * TEN + (size_t)b * SBAT;
        zb = b;
    } else {
        X  = Xb + (long)z * sX;
        Y  = Yb + (long)z * sY;
        Cb = (bf16*)Cv  + (long)z * sC;
        Cf = (float*)Cv + (long)z * sC;
    }
    const int f32o = (EPI == 4) ? *flag : 0;

    const int m0 = by * 128, n0 = bx * 128;
    const int wm = (wave >> 1) * 64, wn = (wave & 1) * 64;
    const int fr = lane & 15, quad = lane >> 4;

    const int srow = tid >> 2;
    const int scol = (tid & 3) * 8;
    const bf16* pX = X + (size_t)(m0 + srow) * lda + scol;
    const bf16* pY = Y + (size_t)(n0 + srow) * ldb + scol;
    const size_t oX = (size_t)64 * lda, oY = (size_t)64 * ldb;
    char* const sb0 = (char*)smem;
    const int ldst = tid * 16;

    auto stage = [&](int k, int pb) {
        char* d = sb0 + pb * 16384;
        const bf16* x = pX + k * 32;
        const bf16* y = pY + k * 32;
        __builtin_amdgcn_global_load_lds((GV*)x,        (SV*)(d + ldst),         16, 0, 0);
        __builtin_amdgcn_global_load_lds((GV*)(x + oX), (SV*)(d + 4096 + ldst),  16, 0, 0);
        __builtin_amdgcn_global_load_lds((GV*)y,        (SV*)(d + 8192 + ldst),  16, 0, 0);
        __builtin_amdgcn_global_load_lds((GV*)(y + oY), (SV*)(d + 12288 + ldst), 16, 0, 0);
    };

    floatx4 acc[4][4] = {};
    const int NK = K >> 5;

    stage(0, 0);
    __syncthreads();

    for (int k = 0; k < NK; ++k) {
        const int p = k & 1;
        if (k + 1 < NK) stage(k + 1, 1 - p);
        const bf16* bA = smem + p * 8192;
        const bf16* bB = bA + 4096;
        bf16x8 af[4], bfr[4];
        #pragma unroll
        for (int i = 0; i < 4; ++i) {
            af[i]  = *(const bf16x8*)&bA[(wm + i * 16 + fr) * 32 + quad * 8];
            bfr[i] = *(const bf16x8*)&bB[(wn + i * 16 + fr) * 32 + quad * 8];
        }
        #pragma unroll
        for (int i = 0; i < 4; ++i)
            #pragma unroll
            for (int j = 0; j < 4; ++j)
                acc[i][j] = __builtin_amdgcn_mfma_f32_16x16x32_bf16(
                    af[i], bfr[j], acc[i][j], 0, 0, 0);
        __syncthreads();
    }

    #pragma unroll
    for (int i = 0; i < 4; ++i) {
        const int mg = m0 + wm + i * 16 + quad * 4;
        float bmr[4], rl[4];
        if (EPI == 1 || EPI == 4) {
            #pragma unroll
            for (int r = 0; r < 4; ++r) bmr[r] = bias[mg + r];
        }
        if (EPI == 3) {
            #pragma unroll
            for (int r = 0; r < 4; ++r)
                rl[r] = 1.0f / fmaxf(lbuf[zb * sL + mg + r], 1e-30f);
        }
        if (EPI == 2) {
            float rs[4] = {0.f, 0.f, 0.f, 0.f};
            #pragma unroll
            for (int j = 0; j < 4; ++j)
                #pragma unroll
                for (int r = 0; r < 4; ++r) {
                    float e = __expf(fminf(acc[i][j][r] * SCALE_QK, 30.f));
                    acc[i][j][r] = e;
                    rs[r] += e;
                }
            #pragma unroll
            for (int r = 0; r < 4; ++r) {
                float v = rs[r];
                v += __shfl_xor(v, 1);
                v += __shfl_xor(v, 2);
                v += __shfl_xor(v, 4);
                v += __shfl_xor(v, 8);
                if (fr == 0) atomicAdd(&lbuf[zb * sL + mg + r], v);
            }
        } else if (EPI != 5) {
            #pragma unroll
            for (int j = 0; j < 4; ++j) {
                const int ng = n0 + wn + j * 16 + fr;
                #pragma unroll
                for (int r = 0; r < 4; ++r) {
                    float v = acc[i][j][r];
                    if (EPI == 0) v += bias[ng];
                    if (EPI == 1) v += bmr[r];
                    if (EPI == 3) v *= rl[r];
                    if (EPI == 4) v += bmr[r];
                    acc[i][j][r] = v;
                }
            }
        }
    }

    if (EPI != 4) {
        bf16* ct = smem;                       // [128][132] bf16
        #pragma unroll
        for (int i = 0; i < 4; ++i)
            #pragma unroll
            for (int j = 0; j < 4; ++j)
                #pragma unroll
                for (int r = 0; r < 4; ++r)
                    ct[(wm + i * 16 + quad * 4 + r) * 132 + wn + j * 16 + fr] =
                        (bf16)acc[i][j][r];
        __syncthreads();
        #pragma unroll
        for (int w = 0; w < 8; ++w) {
            const int idx = w * 2048 + tid * 8;
            const int row = idx >> 7, col = idx & 127;
            bf16x8 v = *(const bf16x8*)&ct[row * 132 + col];
            *(bf16x8*)&Cb[(size_t)(m0 + row) * N + n0 + col] = v;
        }
    } else if (f32o) {
        float* ct = (float*)smem;              // [64][132] f32, two halves
        const float* rres = (const float*)res + (size_t)z * sR;
        #pragma unroll
        for (int h = 0; h < 2; ++h) {
            if ((wave >> 1) == h) {
                #pragma unroll
                for (int i = 0; i < 4; ++i)
                    #pragma unroll
                    for (int j = 0; j < 4; ++j)
                        #pragma unroll
                        for (int r = 0; r < 4; ++r)
                            ct[(i * 16 + quad * 4 + r) * 132 + wn + j * 16 + fr] =
                                acc[i][j][r];
            }
            __syncthreads();
            #pragma unroll
            for (int w = 0; w < 8; ++w) {
                const int idx = (w * 256 + tid) * 4;
                const int row = idx >> 7, col = idx & 127;
                const size_t o = (size_t)(m0 + h * 64 + row) * N + n0 + col;
                floatx4 v = *(const floatx4*)&ct[row * 132 + col];
                floatx4 rv = *(const floatx4*)&rres[o];
                #pragma unroll
                for (int e = 0; e < 4; ++e) v[e] = (v[e] + rv[e]) * INV_SQRT2F;
                *(floatx4*)&Cf[o] = v;
            }
            __syncthreads();
        }
    } else {
        const bf16* resb = (const bf16*)res + (size_t)z * sR;
        #pragma unroll
        for (int i = 0; i < 4; ++i) {
            const int mg = m0 + wm + i * 16 + quad * 4;
            #pragma unroll
            for (int j = 0; j < 4; ++j) {
                const int ng = n0 + wn + j * 16 + fr;
                #pragma unroll
                for (int r = 0; r < 4; ++r) {
                    const size_t o = (size_t)(mg + r) * N + ng;
                    Cb[o] = (bf16)((acc[i][j][r] + (float)resb[o]) * INV_SQRT2F);
                }
            }
        }
    }
}

// ---------------------------------------------------------------------------
extern "C" void kernel_launch(void* const* d_in, const int* in_sizes, int n_in,
                              void* d_out, int out_size, void* d_ws, size_t ws_size,
                              hipStream_t stream)
{
    const void* q     = d_in[0];
    const void* gamma = d_in[1];
    const void* beta  = d_in[2];
    const void* wq    = d_in[3];
    const void* bq    = d_in[4];
    const void* wk    = d_in[5];
    const void* bk    = d_in[6];
    const void* wv    = d_in[7];
    const void* bv    = d_in[8];
    const void* wo    = d_in[9];
    const void* bo    = d_in[10];

    char* w = (char*)d_ws;
    int*   flag = (int*)w;   w += 16;
    float* Pf   = (float*)w; w += 6 * 512 * 4;      // gamma,beta,bq,bk,bv,bo
    bf16*  Wc   = (bf16*)w;  w += 4 * 262144 * 2;   // wq,wk,wv,wo bf16
    bf16*  XN   = (bf16*)w;  w += TEN * 2;          // reused as AOt
    bf16*  Qt   = (bf16*)w;  w += TEN * 2;
    bf16*  V    = (bf16*)w;  w += TEN * 2;
    float* lbuf = (float*)w; w += (size_t)4 * 4096 * 4;
    bf16*  P    = (bf16*)w;
    const size_t base_need = (size_t)(w - (char*)d_ws);
    const bool full = ws_size >= base_need + (size_t)4 * 4096 * 4096 * 2;

    bf16* Kt   = (bf16*)d_out;   // scratch: dead before PV partials land
    bf16* Part = (bf16*)d_out;   // split-K partials [2][4][4096][512]
    bf16* AOt  = XN;

    detect_k<<<dim3(1), 256, 0, stream>>>((const unsigned*)q, flag);
    zero_k<<<dim3(1), 256, 0, stream>>>(lbuf);
    convw_k<<<dim3(128, 4), 256, 0, stream>>>(wq, wk, wv, wo, Wc, flag);
    convp_k<<<dim3(1), 256, 0, stream>>>(gamma, beta, bq, bk, bv, bo, Pf, flag);

    groupnorm_k<<<dim3(128), 256, 0, stream>>>(q, Pf, Pf + 512, XN, flag);

    // Qt[p][o] = XN . Wq^T + bq ; Kt likewise.  N=512, K=512
    gemm_xyt<0><<<dim3(4, 32, 4), 256, 0, stream>>>(XN, Wc + 0 * 262144, Qt,
        512, 512, 512, 512, SBAT, 0, SBAT, Pf + 1024, nullptr, 0, nullptr, 0, flag);
    gemm_xyt<0><<<dim3(4, 32, 4), 256, 0, stream>>>(XN, Wc + 1 * 262144, Kt,
        512, 512, 512, 512, SBAT, 0, SBAT, Pf + 1536, nullptr, 0, nullptr, 0, flag);
    // V[o][p] = Wv . XN^T + bv.  N=4096, K=512
    gemm_xyt<1><<<dim3(32, 4, 4), 256, 0, stream>>>(Wc + 2 * 262144, XN, V,
        4096, 512, 512, 512, 0, SBAT, SBAT, Pf + 2048, nullptr, 0, nullptr, 0, flag);

    if (full) {
        // P[j][i] = exp(scale*<Qt[j],Kt[i]>); lbuf[b][j] += rowsums
        gemm8<2><<<dim3(16, 16, 4), 512, 0, stream>>>(Qt, Kt, P,
            4096, 512, 512, 512, SBAT, SBAT, SPB, lbuf, 4096);
        // PV split-K x2 partials (z = b*2 + s), K=2048 each
        gemm8<5><<<dim3(2, 16, 8), 512, 0, stream>>>(P, V, Part,
            512, 2048, 4096, 4096, 0, 0, 0, nullptr, 0);
        // AOt = (P0 + P1) / l
        reduce_k<<<dim3(4096), 256, 0, stream>>>(Part, lbuf, AOt);
    } else {
        for (int b = 0; b < 4; ++b) {
            gemm_xyt<2><<<dim3(32, 32, 1), 256, 0, stream>>>(
                Qt + (size_t)b * SBAT, Kt + (size_t)b * SBAT, P,
                4096, 512, 512, 512, 0, 0, 0, nullptr,
                lbuf + (size_t)b * 4096, 0, nullptr, 0, flag);
            gemm_xyt<3><<<dim3(4, 32, 1), 256, 0, stream>>>(
                P, V + (size_t)b * SBAT, AOt + (size_t)b * SBAT,
                512, 4096, 4096, 4096, 0, 0, 0, nullptr,
                lbuf + (size_t)b * 4096, 0, nullptr, 0, flag);
        }
    }

    // out[o][p] = (Wo . AOt^T + bo + q) * inv_sqrt2.  N=4096, K=512
    gemm_xyt<4><<<dim3(32, 4, 4), 256, 0, stream>>>(Wc + 3 * 262144, AOt, d_out,
        4096, 512, 512, 512, 0, SBAT, SBAT, Pf + 2560, nullptr, 0, q, SBAT, flag);
}

// Round 3
// 468.498 us; speedup vs baseline: 1.1905x; 1.0346x over previous
//
#include <hip/hip_runtime.h>

typedef __bf16 bf16;
typedef __bf16 bf16x8 __attribute__((ext_vector_type(8)));
typedef float floatx4 __attribute__((ext_vector_type(4)));

#define SCALE_QK 0.044194173824159216f
#define INV_SQRT2F 0.7071067811865476f
#define TEN  8388608L     // elems per activation tensor (4*512*4096)
#define SBAT 2097152L     // elems per batch (4096*512)
#define SPB  16777216L    // P elems per batch (4096*4096)

// address-space helper types for global_load_lds
typedef const __attribute__((address_space(1))) void GV;
typedef __attribute__((address_space(3))) void SV;

// ---------------------------------------------------------------------------
// Dtype detector (verified R3: inputs are f32 -> flag=1; bf16 -> flag=0).
// ---------------------------------------------------------------------------
__global__ __launch_bounds__(256) void detect_k(
    const unsigned* __restrict__ q, int* __restrict__ flag)
{
    __shared__ int cnt;
    if (threadIdx.x == 0) cnt = 0;
    __syncthreads();
    int c = 0;
    for (int i = threadIdx.x; i < 4096; i += 256) {
        unsigned e = (q[i] >> 7) & 0xFFu;
        c += (e >= 100u && e <= 140u) ? 1 : 0;
    }
    atomicAdd(&cnt, c);
    __syncthreads();
    if (threadIdx.x == 0) *flag = (cnt < 3000) ? 1 : 0;
}

__global__ __launch_bounds__(256) void zero_k(float* __restrict__ l)
{
    for (int i = threadIdx.x; i < 16384; i += 256) l[i] = 0.f;
}

__global__ __launch_bounds__(256) void convw_k(
    const void* w0, const void* w1, const void* w2, const void* w3,
    bf16* __restrict__ dst, const int* __restrict__ flag)
{
    const void* srcs[4] = {w0, w1, w2, w3};
    const void* s = srcs[blockIdx.y];
    bf16* d = dst + (size_t)blockIdx.y * 262144;
    const int i = (blockIdx.x * 256 + threadIdx.x) * 8;
    bf16x8 v;
    if (*flag) {
        const float* f = (const float*)s;
        #pragma unroll
        for (int r = 0; r < 8; ++r) v[r] = (bf16)f[i + r];
    } else {
        v = *(const bf16x8*)((const bf16*)s + i);
    }
    *(bf16x8*)(d + i) = v;
}

__global__ __launch_bounds__(256) void convp_k(
    const void* p0, const void* p1, const void* p2,
    const void* p3, const void* p4, const void* p5,
    float* __restrict__ dst, const int* __restrict__ flag)
{
    const void* srcs[6] = {p0, p1, p2, p3, p4, p5};
    const int f = *flag;
    for (int i = threadIdx.x; i < 3072; i += 256) {
        const void* s = srcs[i >> 9];
        const int off = i & 511;
        dst[i] = f ? ((const float*)s)[off] : (float)((const bf16*)s)[off];
    }
}

// ---------------------------------------------------------------------------
// GroupNorm: q [4][512][4096] -> XN [4][4096][512] bf16.
// ---------------------------------------------------------------------------
__global__ __launch_bounds__(256) void groupnorm_k(
    const void* __restrict__ qraw, const float* __restrict__ gamma,
    const float* __restrict__ beta, bf16* __restrict__ XN,
    const int* __restrict__ flag)
{
    const int tid = threadIdx.x;
    const int b = blockIdx.x >> 5, g = blockIdx.x & 31;
    const int f32 = *flag;
    const size_t base = ((size_t)b * 512 + (size_t)g * 16) * 4096;
    const float* sf = (const float*)qraw + base;
    const bf16*  sb = (const bf16*)qraw + base;

    float sum = 0.f, sq = 0.f;
    if (f32) {
        const floatx4* v4 = (const floatx4*)sf;
        for (int idx = tid; idx < 16384; idx += 256) {
            floatx4 v = v4[idx];
            #pragma unroll
            for (int r = 0; r < 4; ++r) { float f = v[r]; sum += f; sq += f * f; }
        }
    } else {
        const bf16x8* v8 = (const bf16x8*)sb;
        for (int idx = tid; idx < 8192; idx += 256) {
            bf16x8 v = v8[idx];
            #pragma unroll
            for (int r = 0; r < 8; ++r) { float f = (float)v[r]; sum += f; sq += f * f; }
        }
    }
    #pragma unroll
    for (int off = 32; off; off >>= 1) {
        sum += __shfl_down(sum, off);
        sq  += __shfl_down(sq, off);
    }
    __shared__ float sS[4], sQ[4];
    __shared__ float s_mean, s_rstd;
    const int wave = tid >> 6, lane = tid & 63;
    if (lane == 0) { sS[wave] = sum; sQ[wave] = sq; }
    __syncthreads();
    if (tid == 0) {
        float ts = sS[0] + sS[1] + sS[2] + sS[3];
        float tq = sQ[0] + sQ[1] + sQ[2] + sQ[3];
        float mean = ts * (1.0f / 65536.0f);
        float var  = tq * (1.0f / 65536.0f) - mean * mean;
        s_mean = mean;
        s_rstd = rsqrtf(fmaxf(var, 0.f) + 1e-6f);
    }
    __syncthreads();
    const float mean = s_mean, rstd = s_rstd;

    float ga[16], be[16];
    #pragma unroll
    for (int c = 0; c < 16; ++c) {
        ga[c] = gamma[g * 16 + c] * rstd;
        be[c] = beta[g * 16 + c] - mean * ga[c];
    }
    bf16* dst = XN + (size_t)b * SBAT + (size_t)g * 16;
    for (int p0 = 0; p0 < 4096; p0 += 256) {
        const int p = p0 + tid;
        bf16x8 o0, o1;
        #pragma unroll
        for (int c = 0; c < 8; ++c) {
            float v = f32 ? sf[(size_t)c * 4096 + p] : (float)sb[(size_t)c * 4096 + p];
            o0[c] = (bf16)(v * ga[c] + be[c]);
        }
        #pragma unroll
        for (int c = 0; c < 8; ++c) {
            float v = f32 ? sf[(size_t)(c + 8) * 4096 + p] : (float)sb[(size_t)(c + 8) * 4096 + p];
            o1[c] = (bf16)(v * ga[c + 8] + be[c + 8]);
        }
        bf16* dp = dst + (size_t)p * 512;
        *(bf16x8*)dp = o0;
        *(bf16x8*)(dp + 8) = o1;
    }
}

// ---------------------------------------------------------------------------
// Reduce split-K partials: AOt = (P0 + P1) / l.  Part: [2][4][4096][512] bf16.
// ---------------------------------------------------------------------------
__global__ __launch_bounds__(256) void reduce_k(
    const bf16* __restrict__ Part, const float* __restrict__ lbuf,
    bf16* __restrict__ AOt)
{
    const size_t i8 = ((size_t)blockIdx.x * 256 + threadIdx.x) * 8;
    const int b = (int)(i8 >> 21);
    const int j = (int)((i8 >> 9) & 4095);
    const float rl = 1.0f / fmaxf(lbuf[b * 4096 + j], 1e-30f);
    bf16x8 a = *(const bf16x8*)&Part[i8];
    bf16x8 c = *(const bf16x8*)&Part[TEN + i8];
    bf16x8 o;
    #pragma unroll
    for (int r = 0; r < 8; ++r) o[r] = (bf16)(((float)a[r] + (float)c[r]) * rl);
    *(bf16x8*)&AOt[i8] = o;
}

// ---------------------------------------------------------------------------
// 256x256 8-phase counted-vmcnt GEMM, C = X . Y^T, k-contig operands.
// 8 waves (2M x 4N), slot = 32 k-cols of A(256)+B(256) = 32KB, 4 slots =
// 128KB LDS, prefetch depth 3 slots, staging loads spread 2-per-phase
// (m196: fine interleave), vmcnt(8) steady state, raw s_barrier.
// LDS XOR-swizzle (pre-swizzled global source + swizzled ds_read).
// P layout is TILED: 256x256 tiles, tile-contiguous 128KB. elem(j,i) at
//   (j>>8)*1048576 + (i>>8)*65536 + (j&255)*256 + (i&255)   [per batch]
// EPI 2 (scores): tiled C store (one sequential 128KB burst per block),
//                 exp(min(acc*SCALE,30)) + atomic rowsum into lbuf.
// EPI 5 (PV split-K): tiled X (P) reads, linear Part store, z = b*2 + s.
// ---------------------------------------------------------------------------
template <int EPI>
__global__ __launch_bounds__(512, 2) void gemm8(
    const bf16* __restrict__ Xb, const bf16* __restrict__ Yb,
    bf16* __restrict__ Cv, int N, int K, int lda, int ldb,
    long sX, long sY, long sC, float* __restrict__ lbuf, long sL)
{
    __shared__ __align__(16) char smc[131072];

    const int tid  = threadIdx.x;
    const int wave = tid >> 6;
    const int lane = tid & 63;
    const int z = blockIdx.z;

    // XCD-aware swizzle: contiguous 2D region per XCD (bijective; gx*gy%8==0)
    int bx = blockIdx.x, by = blockIdx.y;
    {
        const int o = by * gridDim.x + bx;
        const int xcd = o & 7, idx = o >> 3;
        if (gridDim.x == 16) {               // scores 16x16: 4m x 8n regions
            by = (xcd >> 1) * 4 + (idx & 3);
            bx = (xcd & 1) * 8 + (idx >> 2);
        } else {                             // PV 2x16: 2m x 2n regions
            bx = idx & 1;
            by = xcd * 2 + (idx >> 1);
        }
    }

    const bf16* X; const bf16* Y; bf16* Cb;
    if (EPI == 5) {
        const int b = z >> 1, s = z & 1;
        X  = Xb + (size_t)b * SPB  + (size_t)s * 524288;   // tiled P: s -> 8 i-tiles
        Y  = Yb + (size_t)b * SBAT + (size_t)s * 2048;
        Cb = Cv + (size_t)s * TEN + (size_t)b * SBAT;
    } else {
        X  = Xb + (long)z * sX;
        Y  = Yb + (long)z * sY;
        Cb = Cv + (long)z * sC;
    }

    const int m0 = by * 256, n0 = bx * 256;
    const int wm = (wave >> 2) * 128, wn = (wave & 3) * 64;
    const int fr = lane & 15, quad = lane >> 4;

    // ---- staging: thread t -> rows {t>>2, 128+(t>>2)} of A and B, 16B each.
    // LDS dest lane-linear (t*16); source col pre-swizzled (XOR involution).
    const int tq = tid >> 2;
    const int c8 = ((tid & 3) ^ ((tid >> 3) & 3)) << 3;
    const bf16 *gA0, *gA1;
    if (EPI == 5) {      // tiled X: within-tile row stride 256, +128 rows = +32768
        gA0 = X + (size_t)m0 * 4096 + tq * 256 + c8;
        gA1 = gA0 + 32768;
    } else {
        gA0 = X + (size_t)(m0 + tq) * lda + c8;
        gA1 = gA0 + (size_t)128 * lda;
    }
    const bf16* gB0 = Y + (size_t)(n0 + tq) * ldb + c8;
    const bf16* gB1 = gB0 + (size_t)128 * ldb;
    const int ldst = tid * 16;

    auto offX = [&](int h) -> int {
        return (EPI == 5) ? (((h >> 3) << 16) + ((h & 7) << 5)) : (h << 5);
    };
    auto stage_a = [&](int h) {
        char* d = smc + ((h & 3) << 15);
        const int o = offX(h);
        __builtin_amdgcn_global_load_lds((GV*)(gA0 + o), (SV*)(d + ldst),        16, 0, 0);
        __builtin_amdgcn_global_load_lds((GV*)(gA1 + o), (SV*)(d + 8192 + ldst), 16, 0, 0);
    };
    auto stage_b = [&](int h) {
        char* d = smc + ((h & 3) << 15);
        const int o = h << 5;
        __builtin_amdgcn_global_load_lds((GV*)(gB0 + o), (SV*)(d + 16384 + ldst), 16, 0, 0);
        __builtin_amdgcn_global_load_lds((GV*)(gB1 + o), (SV*)(d + 24576 + ldst), 16, 0, 0);
    };

    // ---- fragment read addresses (swizzled; row bits [3:1] come from fr) --
    const int swz = (quad ^ ((fr >> 1) & 3)) << 4;
    const int lbA = (wm + fr) * 64 + swz;            // + m*1024
    const int lbB = 16384 + (wn + fr) * 64 + swz;    // + n*1024

    floatx4 acc[8][4] = {};
    const int H = K >> 5;        // slots of 32 k-cols; H % 4 == 0 (16 or 64)

    stage_a(0); stage_b(0); stage_a(1); stage_b(1); stage_a(2); stage_b(2);
    asm volatile("s_waitcnt vmcnt(8)" ::: "memory");   // slot0 landed
    __builtin_amdgcn_s_barrier();

    #pragma unroll 4
    for (int h = 0; h < H; ++h) {
        const char* sb = smc + ((h & 3) << 15);
        bf16x8 Bf[4], Af[4];
        // ---- phase A: B-frags + A-frags(m 0..3) ; stage A-half of h+3 ----
        #pragma unroll
        for (int n = 0; n < 4; ++n) Bf[n] = *(const bf16x8*)(sb + lbB + n * 1024);
        #pragma unroll
        for (int m = 0; m < 4; ++m) Af[m] = *(const bf16x8*)(sb + lbA + m * 1024);
        if (h + 3 < H) stage_a(h + 3);   // slot (h-1)&3: reuse fenced below
        __builtin_amdgcn_s_barrier();
        __builtin_amdgcn_s_setprio(1);
        #pragma unroll
        for (int m = 0; m < 4; ++m)
            #pragma unroll
            for (int n = 0; n < 4; ++n)
                acc[m][n] = __builtin_amdgcn_mfma_f32_16x16x32_bf16(
                    Af[m], Bf[n], acc[m][n], 0, 0, 0);
        __builtin_amdgcn_s_setprio(0);
        __builtin_amdgcn_s_barrier();
        // ---- phase B: A-frags(m 4..7) ; stage B-half of h+3 ----
        #pragma unroll
        for (int m = 0; m < 4; ++m) Af[m] = *(const bf16x8*)(sb + lbA + (4 + m) * 1024);
        if (h + 3 < H) stage_b(h + 3);
        __builtin_amdgcn_s_barrier();
        __builtin_amdgcn_s_setprio(1);
        #pragma unroll
        for (int m = 0; m < 4; ++m)
            #pragma unroll
            for (int n = 0; n < 4; ++n)
                acc[4 + m][n] = __builtin_amdgcn_mfma_f32_16x16x32_bf16(
                    Af[m], Bf[n], acc[4 + m][n], 0, 0, 0);
        __builtin_amdgcn_s_setprio(0);
        // slot(h+1) readiness: keep the 2 newest slots' stages in flight
        if (h + 3 < H)      { asm volatile("s_waitcnt vmcnt(8)" ::: "memory"); }
        else if (h + 2 < H) { asm volatile("s_waitcnt vmcnt(4)" ::: "memory"); }
        else if (h + 1 < H) { asm volatile("s_waitcnt vmcnt(0)" ::: "memory"); }
        __builtin_amdgcn_s_barrier();   // collectivize readiness + fence reuse
    }
    asm volatile("s_waitcnt vmcnt(0)" ::: "memory");
    __syncthreads();

    // ---- finalize (lane holds D[quad*4+r][fr] of frag (m,n)) ----
    if (EPI == 2) {
        #pragma unroll
        for (int m = 0; m < 8; ++m) {
            const int mg = m0 + wm + m * 16 + quad * 4;
            float rs[4] = {0.f, 0.f, 0.f, 0.f};
            #pragma unroll
            for (int n = 0; n < 4; ++n)
                #pragma unroll
                for (int r = 0; r < 4; ++r) {
                    float e = __expf(fminf(acc[m][n][r] * SCALE_QK, 30.f));
                    acc[m][n][r] = e;
                    rs[r] += e;
                }
            #pragma unroll
            for (int r = 0; r < 4; ++r) {
                float v = rs[r];
                v += __shfl_xor(v, 1);
                v += __shfl_xor(v, 2);
                v += __shfl_xor(v, 4);
                v += __shfl_xor(v, 8);
                if (fr == 0) atomicAdd(&lbuf[z * sL + mg + r], v);
            }
        }
    }

    // ---- staged coalesced stores, two 128-row halves through LDS ----
    bf16* ct = (bf16*)smc;                 // [128][260] bf16 = 66.5KB
    bf16* Ctile = Cb + (size_t)m0 * 4096 + (size_t)n0 * 256;  // EPI2 tiled base
    const int myhalf = wave >> 2;          // waves 0-3: rows 0-127
    #pragma unroll
    for (int half = 0; half < 2; ++half) {
        if (myhalf == half) {
            #pragma unroll
            for (int m = 0; m < 8; ++m)
                #pragma unroll
                for (int n = 0; n < 4; ++n)
                    #pragma unroll
                    for (int r = 0; r < 4; ++r)
                        ct[(m * 16 + quad * 4 + r) * 260 + wn + n * 16 + fr] =
                            (bf16)acc[m][n][r];
        }
        __syncthreads();
        #pragma unroll
        for (int w = 0; w < 8; ++w) {
            const int idx = (w * 512 + tid) * 8;
            const int row = idx >> 8, col = idx & 255;
            bf16x8 v = *(const bf16x8*)&ct[row * 260 + col];
            if (EPI == 2) {
                // tile-contiguous: sequential 128KB burst per block
                *(bf16x8*)&Ctile[((half * 128 + row) << 8) + col] = v;
            } else {
                *(bf16x8*)&Cb[(size_t)(m0 + half * 128 + row) * N + n0 + col] = v;
            }
        }
        __syncthreads();
    }
}

// ---------------------------------------------------------------------------
// 128x128x32 2-phase GEMM (kept for projections + fallback path).
// Epilogues: 0 bias[n] ; 1 bias[m] ; 2 exp+rowsum ; 3 acc/l ; 4 out+res ; 5 raw
// ---------------------------------------------------------------------------
template <int EPI>
__global__ __launch_bounds__(256, 4) void gemm_xyt(
    const bf16* __restrict__ Xb, const bf16* __restrict__ Yb,
    void* __restrict__ Cv, int N, int K, int lda, int ldb,
    long sX, long sY, long sC,
    const float* __restrict__ bias,
    float* __restrict__ lbuf, long sL,
    const void* __restrict__ res, long sR,
    const int* __restrict__ flag)
{
    __shared__ __align__(16) bf16 smem[17408];   // 32KB dbuf, 34KB epilogue

    const int tid  = threadIdx.x;
    const int wave = tid >> 6;
    const int lane = tid & 63;
    const int z = blockIdx.z;

    int bx = blockIdx.x, by = blockIdx.y;
    {
        const int gx = gridDim.x, gy = gridDim.y;
        const int o = by * gx + bx;
        const int xcd = o & 7, idx = o >> 3;
        if (gx == 32 && gy == 32) {
            bx = (xcd & 1) * 16 + (idx & 15);
            by = (xcd >> 1) * 8 + (idx >> 4);
        } else if (gx == 4) {
            bx = idx & 3;
            by = xcd * 4 + (idx >> 2);
        } else if (gx == 32 && gy == 4) {
            bx = (xcd & 1) * 16 + (idx & 15);
            by = xcd >> 1;
        }
    }

    const bf16* X; const bf16* Y; bf16* Cb; float* Cf = nullptr;
    int zb = z;
    if (EPI == 5) {
        const int b = z >> 1, s = z & 1;
        X  = Xb + (size_t)b * SPB  + (size_t)s * 2048;
        Y  = Yb + (size_t)b * SBAT + (size_t)s * 2048;
        Cb = (bf16*)Cv + (size_t)s * TEN + (size_t)b * SBAT;
        zb = b;
    } else {
        X  = Xb + (long)z * sX;
        Y  = Yb + (long)z * sY;
        Cb = (bf16*)Cv  + (long)z * sC;
        Cf = (float*)Cv + (long)z * sC;
    }
    const int f32o = (EPI == 4) ? *flag : 0;

    const int m0 = by * 128, n0 = bx * 128;
    const int wm = (wave >> 1) * 64, wn = (wave & 1) * 64;
    const int fr = lane & 15, quad = lane >> 4;

    const int srow = tid >> 2;
    const int scol = (tid & 3) * 8;
    const bf16* pX = X + (size_t)(m0 + srow) * lda + scol;
    const bf16* pY = Y + (size_t)(n0 + srow) * ldb + scol;
    const size_t oX = (size_t)64 * lda, oY = (size_t)64 * ldb;
    char* const sb0 = (char*)smem;
    const int ldst = tid * 16;

    auto stage = [&](int k, int pb) {
        char* d = sb0 + pb * 16384;
        const bf16* x = pX + k * 32;
        const bf16* y = pY + k * 32;
        __builtin_amdgcn_global_load_lds((GV*)x,        (SV*)(d + ldst),         16, 0, 0);
        __builtin_amdgcn_global_load_lds((GV*)(x + oX), (SV*)(d + 4096 + ldst),  16, 0, 0);
        __builtin_amdgcn_global_load_lds((GV*)y,        (SV*)(d + 8192 + ldst),  16, 0, 0);
        __builtin_amdgcn_global_load_lds((GV*)(y + oY), (SV*)(d + 12288 + ldst), 16, 0, 0);
    };

    floatx4 acc[4][4] = {};
    const int NK = K >> 5;

    stage(0, 0);
    __syncthreads();

    for (int k = 0; k < NK; ++k) {
        const int p = k & 1;
        if (k + 1 < NK) stage(k + 1, 1 - p);
        const bf16* bA = smem + p * 8192;
        const bf16* bB = bA + 4096;
        bf16x8 af[4], bfr[4];
        #pragma unroll
        for (int i = 0; i < 4; ++i) {
            af[i]  = *(const bf16x8*)&bA[(wm + i * 16 + fr) * 32 + quad * 8];
            bfr[i] = *(const bf16x8*)&bB[(wn + i * 16 + fr) * 32 + quad * 8];
        }
        #pragma unroll
        for (int i = 0; i < 4; ++i)
            #pragma unroll
            for (int j = 0; j < 4; ++j)
                acc[i][j] = __builtin_amdgcn_mfma_f32_16x16x32_bf16(
                    af[i], bfr[j], acc[i][j], 0, 0, 0);
        __syncthreads();
    }

    #pragma unroll
    for (int i = 0; i < 4; ++i) {
        const int mg = m0 + wm + i * 16 + quad * 4;
        float bmr[4], rl[4];
        if (EPI == 1 || EPI == 4) {
            #pragma unroll
            for (int r = 0; r < 4; ++r) bmr[r] = bias[mg + r];
        }
        if (EPI == 3) {
            #pragma unroll
            for (int r = 0; r < 4; ++r)
                rl[r] = 1.0f / fmaxf(lbuf[zb * sL + mg + r], 1e-30f);
        }
        if (EPI == 2) {
            float rs[4] = {0.f, 0.f, 0.f, 0.f};
            #pragma unroll
            for (int j = 0; j < 4; ++j)
                #pragma unroll
                for (int r = 0; r < 4; ++r) {
                    float e = __expf(fminf(acc[i][j][r] * SCALE_QK, 30.f));
                    acc[i][j][r] = e;
                    rs[r] += e;
                }
            #pragma unroll
            for (int r = 0; r < 4; ++r) {
                float v = rs[r];
                v += __shfl_xor(v, 1);
                v += __shfl_xor(v, 2);
                v += __shfl_xor(v, 4);
                v += __shfl_xor(v, 8);
                if (fr == 0) atomicAdd(&lbuf[zb * sL + mg + r], v);
            }
        } else if (EPI != 5) {
            #pragma unroll
            for (int j = 0; j < 4; ++j) {
                const int ng = n0 + wn + j * 16 + fr;
                #pragma unroll
                for (int r = 0; r < 4; ++r) {
                    float v = acc[i][j][r];
                    if (EPI == 0) v += bias[ng];
                    if (EPI == 1) v += bmr[r];
                    if (EPI == 3) v *= rl[r];
                    if (EPI == 4) v += bmr[r];
                    acc[i][j][r] = v;
                }
            }
        }
    }

    if (EPI != 4) {
        bf16* ct = smem;                       // [128][132] bf16
        #pragma unroll
        for (int i = 0; i < 4; ++i)
            #pragma unroll
            for (int j = 0; j < 4; ++j)
                #pragma unroll
                for (int r = 0; r < 4; ++r)
                    ct[(wm + i * 16 + quad * 4 + r) * 132 + wn + j * 16 + fr] =
                        (bf16)acc[i][j][r];
        __syncthreads();
        #pragma unroll
        for (int w = 0; w < 8; ++w) {
            const int idx = w * 2048 + tid * 8;
            const int row = idx >> 7, col = idx & 127;
            bf16x8 v = *(const bf16x8*)&ct[row * 132 + col];
            *(bf16x8*)&Cb[(size_t)(m0 + row) * N + n0 + col] = v;
        }
    } else if (f32o) {
        float* ct = (float*)smem;              // [64][132] f32, two halves
        const float* rres = (const float*)res + (size_t)z * sR;
        #pragma unroll
        for (int h = 0; h < 2; ++h) {
            if ((wave >> 1) == h) {
                #pragma unroll
                for (int i = 0; i < 4; ++i)
                    #pragma unroll
                    for (int j = 0; j < 4; ++j)
                        #pragma unroll
                        for (int r = 0; r < 4; ++r)
                            ct[(i * 16 + quad * 4 + r) * 132 + wn + j * 16 + fr] =
                                acc[i][j][r];
            }
            __syncthreads();
            #pragma unroll
            for (int w = 0; w < 8; ++w) {
                const int idx = (w * 256 + tid) * 4;
                const int row = idx >> 7, col = idx & 127;
                const size_t o = (size_t)(m0 + h * 64 + row) * N + n0 + col;
                floatx4 v = *(const floatx4*)&ct[row * 132 + col];
                floatx4 rv = *(const floatx4*)&rres[o];
                #pragma unroll
                for (int e = 0; e < 4; ++e) v[e] = (v[e] + rv[e]) * INV_SQRT2F;
                *(floatx4*)&Cf[o] = v;
            }
            __syncthreads();
        }
    } else {
        const bf16* resb = (const bf16*)res + (size_t)z * sR;
        #pragma unroll
        for (int i = 0; i < 4; ++i) {
            const int mg = m0 + wm + i * 16 + quad * 4;
            #pragma unroll
            for (int j = 0; j < 4; ++j) {
                const int ng = n0 + wn + j * 16 + fr;
                #pragma unroll
                for (int r = 0; r < 4; ++r) {
                    const size_t o = (size_t)(mg + r) * N + ng;
                    Cb[o] = (bf16)((acc[i][j][r] + (float)resb[o]) * INV_SQRT2F);
                }
            }
        }
    }
}

// ---------------------------------------------------------------------------
extern "C" void kernel_launch(void* const* d_in, const int* in_sizes, int n_in,
                              void* d_out, int out_size, void* d_ws, size_t ws_size,
                              hipStream_t stream)
{
    const void* q     = d_in[0];
    const void* gamma = d_in[1];
    const void* beta  = d_in[2];
    const void* wq    = d_in[3];
    const void* bq    = d_in[4];
    const void* wk    = d_in[5];
    const void* bk    = d_in[6];
    const void* wv    = d_in[7];
    const void* bv    = d_in[8];
    const void* wo    = d_in[9];
    const void* bo    = d_in[10];

    char* w = (char*)d_ws;
    int*   flag = (int*)w;   w += 16;
    float* Pf   = (float*)w; w += 6 * 512 * 4;      // gamma,beta,bq,bk,bv,bo
    bf16*  Wc   = (bf16*)w;  w += 4 * 262144 * 2;   // wq,wk,wv,wo bf16
    bf16*  XN   = (bf16*)w;  w += TEN * 2;          // reused as AOt
    bf16*  Qt   = (bf16*)w;  w += TEN * 2;
    bf16*  V    = (bf16*)w;  w += TEN * 2;
    float* lbuf = (float*)w; w += (size_t)4 * 4096 * 4;
    bf16*  P    = (bf16*)w;
    const size_t base_need = (size_t)(w - (char*)d_ws);
    const bool full = ws_size >= base_need + (size_t)4 * 4096 * 4096 * 2;

    bf16* Kt   = (bf16*)d_out;   // scratch: dead before PV partials land
    bf16* Part = (bf16*)d_out;   // split-K partials [2][4][4096][512]
    bf16* AOt  = XN;

    detect_k<<<dim3(1), 256, 0, stream>>>((const unsigned*)q, flag);
    zero_k<<<dim3(1), 256, 0, stream>>>(lbuf);
    convw_k<<<dim3(128, 4), 256, 0, stream>>>(wq, wk, wv, wo, Wc, flag);
    convp_k<<<dim3(1), 256, 0, stream>>>(gamma, beta, bq, bk, bv, bo, Pf, flag);

    groupnorm_k<<<dim3(128), 256, 0, stream>>>(q, Pf, Pf + 512, XN, flag);

    // Qt[p][o] = XN . Wq^T + bq ; Kt likewise.  N=512, K=512
    gemm_xyt<0><<<dim3(4, 32, 4), 256, 0, stream>>>(XN, Wc + 0 * 262144, Qt,
        512, 512, 512, 512, SBAT, 0, SBAT, Pf + 1024, nullptr, 0, nullptr, 0, flag);
    gemm_xyt<0><<<dim3(4, 32, 4), 256, 0, stream>>>(XN, Wc + 1 * 262144, Kt,
        512, 512, 512, 512, SBAT, 0, SBAT, Pf + 1536, nullptr, 0, nullptr, 0, flag);
    // V[o][p] = Wv . XN^T + bv.  N=4096, K=512
    gemm_xyt<1><<<dim3(32, 4, 4), 256, 0, stream>>>(Wc + 2 * 262144, XN, V,
        4096, 512, 512, 512, 0, SBAT, SBAT, Pf + 2048, nullptr, 0, nullptr, 0, flag);

    if (full) {
        // P(tiled)[j,i] = exp(scale*<Qt[j],Kt[i]>); lbuf[b][j] += rowsums
        gemm8<2><<<dim3(16, 16, 4), 512, 0, stream>>>(Qt, Kt, P,
            4096, 512, 512, 512, SBAT, SBAT, SPB, lbuf, 4096);
        // PV split-K x2 partials (z = b*2 + s), K=2048 each; X = tiled P
        gemm8<5><<<dim3(2, 16, 8), 512, 0, stream>>>(P, V, Part,
            512, 2048, 4096, 4096, 0, 0, 0, nullptr, 0);
        // AOt = (P0 + P1) / l
        reduce_k<<<dim3(4096), 256, 0, stream>>>(Part, lbuf, AOt);
    } else {
        for (int b = 0; b < 4; ++b) {
            gemm_xyt<2><<<dim3(32, 32, 1), 256, 0, stream>>>(
                Qt + (size_t)b * SBAT, Kt + (size_t)b * SBAT, P,
                4096, 512, 512, 512, 0, 0, 0, nullptr,
                lbuf + (size_t)b * 4096, 0, nullptr, 0, flag);
            gemm_xyt<3><<<dim3(4, 32, 1), 256, 0, stream>>>(
                P, V + (size_t)b * SBAT, AOt + (size_t)b * SBAT,
                512, 4096, 4096, 4096, 0, 0, 0, nullptr,
                lbuf + (size_t)b * 4096, 0, nullptr, 0, flag);
        }
    }

    // out[o][p] = (Wo . AOt^T + bo + q) * inv_sqrt2.  N=4096, K=512
    gemm_xyt<4><<<dim3(32, 4, 4), 256, 0, stream>>>(Wc + 3 * 262144, AOt, d_out,
        4096, 512, 512, 512, 0, SBAT, SBAT, Pf + 2560, nullptr, 0, q, SBAT, flag);
}